// Round 10
// baseline (881.731 us; speedup 1.0000x reference)
//
#include <hip/hip_runtime.h>
#include <math.h>

#define N_TOKENS 32768
#define N_EMBED  8192
#define EMB      32
#define DECAYF   0.99f
#define OMDF     0.01f

// ---- workspace layout (float-element offsets) ----
#define WS_ZN    0                         // normalized z   [N_TOKENS*EMB]
#define WS_WW    (N_TOKENS*EMB)            // ||w||^2        [N_EMBED]
#define WS_ENC   (WS_WW + N_EMBED)         // indices (int)  [N_TOKENS]
#define WS_BINS  (WS_ENC + N_TOKENS)       // counts         [N_EMBED]
#define WS_ESUM  (WS_BINS + N_EMBED)       // scatter sum    [N_EMBED*EMB]
#define WS_LOSS  (WS_ESUM + N_EMBED*EMB)   // loss accum     [1]

// ---- output layout (float-element offsets), reference return order ----
#define OUT_ZQ   0
#define OUT_LOSS (N_TOKENS*EMB)            // 1048576
#define OUT_IDX  (OUT_LOSS + 1)            // 1048577
#define OUT_NW   (OUT_IDX + N_TOKENS)      // 1081345
#define OUT_CS   (OUT_NW + N_EMBED*EMB)    // 1343489

// ============ K0a: normalize z rows -> zn (ws) ============
__global__ void k_prep(const float* __restrict__ z, float* __restrict__ zn) {
    int t = blockIdx.x * blockDim.x + threadIdx.x;
    const float4* zp = (const float4*)(z + (size_t)t * EMB);
    float4 v[8];
    float acc = 0.f;
#pragma unroll
    for (int i = 0; i < 8; ++i) {
        v[i] = zp[i];
        acc += v[i].x * v[i].x + v[i].y * v[i].y + v[i].z * v[i].z + v[i].w * v[i].w;
    }
    float n = fmaxf(sqrtf(acc), 1e-12f);
    float4* o = (float4*)(zn + (size_t)t * EMB);
#pragma unroll
    for (int i = 0; i < 8; ++i) {
        float4 r;
        r.x = v[i].x / n; r.y = v[i].y / n; r.z = v[i].z / n; r.w = v[i].w / n;
        o[i] = r;
    }
}

// ============ K0b: ||w||^2 per codebook row ============
__global__ void k_ww(const float* __restrict__ w, float* __restrict__ ww) {
    int r = blockIdx.x * blockDim.x + threadIdx.x;
    if (r >= N_EMBED) return;
    const float4* wp = (const float4*)(w + (size_t)r * EMB);
    float acc = 0.f;
#pragma unroll
    for (int i = 0; i < 8; ++i) {
        float4 v = wp[i];
        acc += v.x * v.x + v.y * v.y + v.z * v.z + v.w * v.w;
    }
    ww[r] = acc;
}

// ============ K1: distance + argmin, inverted ownership ============
// r5-r8 lesson: a long-lived per-lane z-tile gets demoted to scratch no matter
// what (VGPR 28/40/52/56 across 4 attempts). Invert: LANE owns a codebook row
// (32 floats, live for ONE chunk, ping-pong prefetched), WAVE owns 16 tokens
// whose normalized z rows are wave-uniform -> s_load/SGPR broadcast per chunk.
// Long-lived per-lane state = best[16]/bidx[16] accumulators only (never
// spilled). Each wave scans the whole codebook -> single in-wave butterfly
// finishes the argmin; no LDS, no cross-wave combine.
// Key = ww[n] - 2*dot(zn, w[n]) — identical formulation to the passing r6.
#define TOKS_PER_WAVE 16
#define WAVES_PER_BLOCK 8
#define CHUNKS (N_EMBED / 64)              // 128

#define LOADW(BUF, CC) do {                                                    \
    const float4* wp_ = (const float4*)(weight + ((size_t)((CC) * 64 + lane)) * EMB); \
    _Pragma("unroll")                                                          \
    for (int q_ = 0; q_ < 8; ++q_) {                                           \
        float4 v_ = wp_[q_];                                                   \
        BUF[4*q_+0] = v_.x; BUF[4*q_+1] = v_.y;                                \
        BUF[4*q_+2] = v_.z; BUF[4*q_+3] = v_.w;                                \
    }                                                                          \
} while (0)

#define COMPUTE(W, WWV, CC) do {                                               \
    const int rowbase_ = (CC) * 64 + lane;                                     \
    _Pragma("unroll")                                                          \
    for (int t_ = 0; t_ < TOKS_PER_WAVE; ++t_) {                               \
        const float* zt_ = zb + t_ * EMB;                                      \
        float d0_ = 0.f, d1_ = 0.f, d2_ = 0.f, d3_ = 0.f;                      \
        _Pragma("unroll")                                                      \
        for (int k_ = 0; k_ < 8; ++k_) {                                       \
            d0_ = fmaf(W[4*k_+0], zt_[4*k_+0], d0_);                           \
            d1_ = fmaf(W[4*k_+1], zt_[4*k_+1], d1_);                           \
            d2_ = fmaf(W[4*k_+2], zt_[4*k_+2], d2_);                           \
            d3_ = fmaf(W[4*k_+3], zt_[4*k_+3], d3_);                           \
        }                                                                      \
        float key_ = fmaf(-2.f, (d0_ + d1_) + (d2_ + d3_), WWV);               \
        bool c_ = key_ < best[t_];      /* strict <: first-min per lane */     \
        best[t_] = c_ ? key_ : best[t_];                                       \
        bidx[t_] = c_ ? rowbase_ : bidx[t_];                                   \
    }                                                                          \
} while (0)

__global__ __attribute__((amdgpu_flat_work_group_size(512, 512),
                          amdgpu_waves_per_eu(2, 2)))
void k_argmin(const float* __restrict__ zn, const float* __restrict__ weight,
              const float* __restrict__ ww, int* __restrict__ enc) {
    const int lane = threadIdx.x & 63;
    const int wv   = __builtin_amdgcn_readfirstlane(threadIdx.x >> 6);
    const int wid  = blockIdx.x * WAVES_PER_BLOCK + wv;
    const int tok0 = wid * TOKS_PER_WAVE;
    const float* zb = zn + (size_t)tok0 * EMB;   // wave-uniform base -> s_load path

    float best[TOKS_PER_WAVE];
    int   bidx[TOKS_PER_WAVE];
#pragma unroll
    for (int t = 0; t < TOKS_PER_WAVE; ++t) { best[t] = 3.4e38f; bidx[t] = 0; }

    float wA[32], wB[32];
    float wwA, wwB;

    LOADW(wA, 0);
    wwA = ww[lane];

#pragma unroll 1
    for (int c = 0; c < CHUNKS; c += 2) {
        // prefetch chunk c+1 while computing chunk c
        LOADW(wB, c + 1);
        wwB = ww[(c + 1) * 64 + lane];
        COMPUTE(wA, wwA, c);

        // prefetch chunk c+2 while computing chunk c+1 (last iter: dummy reload of 0)
        const int cn = (c + 2 < CHUNKS) ? (c + 2) : 0;
        LOADW(wA, cn);
        wwA = ww[cn * 64 + lane];
        COMPUTE(wB, wwB, c + 1);
    }

    // in-wave butterfly: lexicographic (key, idx) min == jnp.argmin first-min
#pragma unroll
    for (int t = 0; t < TOKS_PER_WAVE; ++t) {
        float b = best[t];
        int   bi = bidx[t];
#pragma unroll
        for (int off = 32; off >= 1; off >>= 1) {
            float ob = __shfl_xor(b, off, 64);
            int   oi = __shfl_xor(bi, off, 64);
            bool c2 = (ob < b) || (ob == b && oi < bi);
            b  = c2 ? ob : b;
            bi = c2 ? oi : bi;
        }
        if (lane == 0) enc[tok0 + t] = bi;
    }
}

// ============ K3: per-token outputs + scatters + loss ============
__global__ void k_token(const float* __restrict__ zn, const float* __restrict__ weight,
                        const int* __restrict__ enc, float* __restrict__ out,
                        float* __restrict__ bins, float* __restrict__ esum,
                        float* __restrict__ loss) {
    int t = blockIdx.x * blockDim.x + threadIdx.x;
    int idx = enc[t];
    const float4* zp = (const float4*)(zn + (size_t)t * EMB);
    const float4* wp = (const float4*)(weight + (size_t)idx * EMB);
    float4* oq = (float4*)(out + OUT_ZQ + (size_t)t * EMB);

    float lacc = 0.f;
#pragma unroll
    for (int i = 0; i < 8; ++i) {
        float4 zv = zp[i];
        float4 wv = wp[i];
        float4 d, o;
        d.x = wv.x - zv.x; d.y = wv.y - zv.y; d.z = wv.z - zv.z; d.w = wv.w - zv.w;
        lacc += d.x * d.x + d.y * d.y + d.z * d.z + d.w * d.w;
        // straight-through: z + (z_q - z), replicating reference fp rounding
        o.x = zv.x + d.x; o.y = zv.y + d.y; o.z = zv.z + d.z; o.w = zv.w + d.w;
        oq[i] = o;
        atomicAdd(esum + (size_t)idx * EMB + 4 * i + 0, zv.x);
        atomicAdd(esum + (size_t)idx * EMB + 4 * i + 1, zv.y);
        atomicAdd(esum + (size_t)idx * EMB + 4 * i + 2, zv.z);
        atomicAdd(esum + (size_t)idx * EMB + 4 * i + 3, zv.w);
    }
    out[OUT_IDX + t] = (float)idx;
    atomicAdd(bins + idx, 1.0f);

    // wave-level loss reduction, one atomic per wave
#pragma unroll
    for (int off = 32; off > 0; off >>= 1) lacc += __shfl_xor(lacc, off, 64);
    if ((threadIdx.x & 63) == 0) atomicAdd(loss, lacc);
}

// ============ K4: EMA codebook update + finalize loss ============
__global__ void k_ema(const float* __restrict__ weight, const float* __restrict__ cs,
                      const float* __restrict__ bins, const float* __restrict__ esum,
                      const float* __restrict__ loss, float* __restrict__ out) {
    int n = blockIdx.x * blockDim.x + threadIdx.x;
    if (n == 0) {
        out[OUT_LOSS] = loss[0] * (1.0f / (float)(N_TOKENS * EMB));  // BETA = 1
    }
    if (n >= N_EMBED) return;

    float b = bins[n];
    out[OUT_CS + n] = cs[n] * DECAYF + b * OMDF;

    bool zero = (b == 0.0f);
    float safe = zero ? 1.0f : b;

    float w[EMB], en[EMB];
    const float* wrow = weight + (size_t)n * EMB;
    const float* erow = esum + (size_t)n * EMB;
    float nacc = 0.f;
#pragma unroll
    for (int i = 0; i < EMB; ++i) {
        w[i] = wrow[i];
        en[i] = erow[i] / safe;
        nacc += en[i] * en[i];
    }
    float nn = fmaxf(sqrtf(nacc), 1e-12f);
#pragma unroll
    for (int i = 0; i < EMB; ++i) {
        en[i] = zero ? w[i] : (en[i] / nn);
    }
    float acc2 = 0.f;
    float nw[EMB];
#pragma unroll
    for (int i = 0; i < EMB; ++i) {
        nw[i] = w[i] * DECAYF + en[i] * OMDF;
        acc2 += nw[i] * nw[i];
    }
    float n2 = fmaxf(sqrtf(acc2), 1e-12f);
#pragma unroll
    for (int i = 0; i < EMB; ++i) {
        out[OUT_NW + (size_t)n * EMB + i] = nw[i] / n2;
    }
}

// ============ launcher ============
extern "C" void kernel_launch(void* const* d_in, const int* in_sizes, int n_in,
                              void* d_out, int out_size, void* d_ws, size_t ws_size,
                              hipStream_t stream) {
    const float* z  = (const float*)d_in[0];
    const float* w  = (const float*)d_in[1];
    const float* cs = (const float*)d_in[2];
    float* out = (float*)d_out;
    float* ws  = (float*)d_ws;

    float* zn   = ws + WS_ZN;
    float* ww   = ws + WS_WW;
    int*   enc  = (int*)(ws + WS_ENC);
    float* bins = ws + WS_BINS;
    float* esum = ws + WS_ESUM;
    float* loss = ws + WS_LOSS;

    // zero the accumulators (bins, esum, loss are contiguous)
    hipMemsetAsync(bins, 0, (size_t)(N_EMBED + N_EMBED * EMB + 1) * sizeof(float), stream);

    k_prep<<<N_TOKENS / 256, 256, 0, stream>>>(z, zn);
    k_ww<<<N_EMBED / 256, 256, 0, stream>>>(w, ww);
    k_argmin<<<N_TOKENS / (TOKS_PER_WAVE * WAVES_PER_BLOCK), 512, 0, stream>>>(zn, w, ww, enc);
    k_token<<<N_TOKENS / 256, 256, 0, stream>>>(zn, w, enc, out, bins, esum, loss);
    k_ema<<<(N_EMBED + 255) / 256, 256, 0, stream>>>(w, cs, bins, esum, loss, out);
}

// Round 11
// 758.573 us; speedup vs baseline: 1.1624x; 1.1624x over previous
//
#include <hip/hip_runtime.h>
#include <math.h>

#define N_TOKENS 32768
#define N_EMBED  8192
#define EMB      32
#define DECAYF   0.99f
#define OMDF     0.01f
#define EPSK     2e-4f
#define CAND_CAP 65536

typedef unsigned short ushortT;
typedef __attribute__((ext_vector_type(8))) short short8;
typedef __attribute__((ext_vector_type(4))) float f32x4;

// ---- ws layout (float-element offsets) ----
#define WS_WHI  0                          // ushort[8192*32] -> 131072 floats
#define WS_WLO  (WS_WHI + 131072)          // ushort[8192*32]
#define WS_WWN  (WS_WLO + 131072)          // -ww/2          [8192]
#define WS_THR  (WS_WWN + N_EMBED)         // exact thr      [32768]
#define WS_PACK (WS_THR + N_TOKENS)        // u64[32768] -> 65536 floats (8B-aligned: even offset)
#define WS_BINS (WS_PACK + 2*N_TOKENS)
#define WS_ESUM (WS_BINS + N_EMBED)
#define WS_LOSS (WS_ESUM + N_EMBED*EMB)
#define WS_CCNT (WS_LOSS + 1)              // uint
#define WS_CAND (WS_CCNT + 1)              // u64[CAND_CAP]  (offset 638978: even -> 8B aligned)

// ---- out layout (float-element offsets), reference return order ----
#define OUT_ZQ   0
#define OUT_LOSS (N_TOKENS*EMB)
#define OUT_IDX  (OUT_LOSS + 1)
#define OUT_NW   (OUT_IDX + N_TOKENS)
#define OUT_CS   (OUT_NW + N_EMBED*EMB)
// zhi/zlo bf16 scratch lives in out[OUT_ZQ] (4MB exactly); overwritten by k_token at the end.

// ---- shared numerics (bitwise-identical across all exact-path users) ----
__device__ __forceinline__ ushortT bf16rn(float x) {
    unsigned b = __float_as_uint(x);
    unsigned r = (b + 0x7FFFu + ((b >> 16) & 1u)) >> 16;
    return (ushortT)r;
}
__device__ __forceinline__ float bf16tof(ushortT u) {
    return __uint_as_float(((unsigned)u) << 16);
}
__device__ __forceinline__ void load_zn_row(const float* __restrict__ z, int t, float* zr) {
    const float4* zp = (const float4*)(z + (size_t)t * EMB);
    float acc = 0.f;
#pragma unroll
    for (int i = 0; i < 8; ++i) {
        float4 v = zp[i];
        zr[4*i+0] = v.x; zr[4*i+1] = v.y; zr[4*i+2] = v.z; zr[4*i+3] = v.w;
        acc += v.x*v.x + v.y*v.y + v.z*v.z + v.w*v.w;
    }
    float n = fmaxf(sqrtf(acc), 1e-12f);
#pragma unroll
    for (int k = 0; k < EMB; ++k) zr[k] = zr[k] / n;
}
__device__ __forceinline__ float exact_key(const float* zr, const float* __restrict__ wrow, float ww) {
    float d0 = 0.f, d1 = 0.f, d2 = 0.f, d3 = 0.f;
#pragma unroll
    for (int k = 0; k < 8; ++k) {
        d0 = fmaf(zr[4*k+0], wrow[4*k+0], d0);
        d1 = fmaf(zr[4*k+1], wrow[4*k+1], d1);
        d2 = fmaf(zr[4*k+2], wrow[4*k+2], d2);
        d3 = fmaf(zr[4*k+3], wrow[4*k+3], d3);
    }
    return fmaf(-2.f, (d0 + d1) + (d2 + d3), ww);
}
__device__ __forceinline__ unsigned long long packkey(float k, int idx) {
    unsigned u = __float_as_uint(k);
    u = (u & 0x80000000u) ? ~u : (u | 0x80000000u);   // sortable-float map
    return (((unsigned long long)u) << 32) | (unsigned)idx;
}

// ============ K_prep: normalize z + split to bf16 hi/lo (stored in out) ============
__global__ void k_prep(const float* __restrict__ z, ushortT* __restrict__ zhi,
                       ushortT* __restrict__ zlo) {
    int t = blockIdx.x * blockDim.x + threadIdx.x;
    float zr[EMB];
    load_zn_row(z, t, zr);
    unsigned h[16], l[16];
#pragma unroll
    for (int i = 0; i < 16; ++i) {
        ushortT h0 = bf16rn(zr[2*i]), h1 = bf16rn(zr[2*i+1]);
        float r0 = zr[2*i] - bf16tof(h0), r1 = zr[2*i+1] - bf16tof(h1);
        ushortT l0 = bf16rn(r0), l1 = bf16rn(r1);
        h[i] = (unsigned)h0 | ((unsigned)h1 << 16);
        l[i] = (unsigned)l0 | ((unsigned)l1 << 16);
    }
    uint4* dh = (uint4*)(zhi + (size_t)t * EMB);
    uint4* dl = (uint4*)(zlo + (size_t)t * EMB);
#pragma unroll
    for (int q = 0; q < 4; ++q) {
        dh[q] = make_uint4(h[4*q], h[4*q+1], h[4*q+2], h[4*q+3]);
        dl[q] = make_uint4(l[4*q], l[4*q+1], l[4*q+2], l[4*q+3]);
    }
}

// ============ K_wprep: split weight + wwn = -||w||^2/2 ============
__global__ void k_wprep(const float* __restrict__ w, ushortT* __restrict__ whi,
                        ushortT* __restrict__ wlo, float* __restrict__ wwn) {
    int r = blockIdx.x * blockDim.x + threadIdx.x;
    if (r >= N_EMBED) return;
    const float4* wp = (const float4*)(w + (size_t)r * EMB);
    float wr[EMB];
    float acc = 0.f;
#pragma unroll
    for (int i = 0; i < 8; ++i) {
        float4 v = wp[i];
        wr[4*i+0] = v.x; wr[4*i+1] = v.y; wr[4*i+2] = v.z; wr[4*i+3] = v.w;
        acc += v.x*v.x + v.y*v.y + v.z*v.z + v.w*v.w;
    }
    wwn[r] = -0.5f * acc;
    unsigned h[16], l[16];
#pragma unroll
    for (int i = 0; i < 16; ++i) {
        ushortT h0 = bf16rn(wr[2*i]), h1 = bf16rn(wr[2*i+1]);
        float r0 = wr[2*i] - bf16tof(h0), r1 = wr[2*i+1] - bf16tof(h1);
        ushortT l0 = bf16rn(r0), l1 = bf16rn(r1);
        h[i] = (unsigned)h0 | ((unsigned)h1 << 16);
        l[i] = (unsigned)l0 | ((unsigned)l1 << 16);
    }
    uint4* dh = (uint4*)(whi + (size_t)r * EMB);
    uint4* dl = (uint4*)(wlo + (size_t)r * EMB);
#pragma unroll
    for (int q = 0; q < 4; ++q) {
        dh[q] = make_uint4(h[4*q], h[4*q+1], h[4*q+2], h[4*q+3]);
        dl[q] = make_uint4(l[4*q], l[4*q+1], l[4*q+2], l[4*q+3]);
    }
}

// ============ K_scan<MODE>: split-bf16 MFMA distance scan ============
// Wave owns 32 tokens (2 chains x 16); scans all 512 n-tiles of 16 codebook
// rows. Per tile: 3 chained MFMAs per chain (lo*hi + hi*lo + hi*hi) seeded
// with C = -ww/2, so C = dot - ww/2 and key = -2C; argmin key == argmax C.
// A-frag: lane reads zhi[(tok0+c*16+(lane&15))*32 + 8*(lane>>4) .. +8]  (M=row=lane&15)
// B-frag: lane reads whi[(n0    +(lane&15))*32 + 8*(lane>>4) .. +8]    (N=col=lane&15)
// D: col n = lane&15, row m = (lane>>4)*4 + reg  [guide §3, m89/m91-verified]
// MODE 0: track per-lane argmax, butterfly over 16-lane groups, write packed.
// MODE 1: flag keys <= thr[token] into candidate list (rare; ~1/token).
template<int MODE>
__global__ __launch_bounds__(256) void k_scan(
        const ushortT* __restrict__ zhi, const ushortT* __restrict__ zlo,
        const ushortT* __restrict__ whi, const ushortT* __restrict__ wlo,
        const float* __restrict__ wwn, const float* __restrict__ thr,
        unsigned long long* __restrict__ packed,
        unsigned* __restrict__ ccnt, unsigned long long* __restrict__ cand) {
    const int lane = threadIdx.x & 63;
    const int wv   = threadIdx.x >> 6;
    const int wid  = blockIdx.x * 4 + wv;
    const int tok0 = wid * 32;
    const int l15  = lane & 15;
    const int lg   = lane >> 4;

    const size_t aoff0 = ((size_t)(tok0 + l15)) * EMB + 8 * lg;
    const size_t aoff1 = ((size_t)(tok0 + 16 + l15)) * EMB + 8 * lg;
    const short8 a0h = *(const short8*)(zhi + aoff0);
    const short8 a0l = *(const short8*)(zlo + aoff0);
    const short8 a1h = *(const short8*)(zhi + aoff1);
    const short8 a1l = *(const short8*)(zlo + aoff1);

    float best0[4], best1[4];
    int   bid0[4], bid1[4];
    float thrv0[4], thrv1[4];
    if (MODE == 0) {
#pragma unroll
        for (int r = 0; r < 4; ++r) {
            best0[r] = -3.4e38f; best1[r] = -3.4e38f; bid0[r] = 0; bid1[r] = 0;
        }
    } else {
#pragma unroll
        for (int r = 0; r < 4; ++r) {
            thrv0[r] = thr[tok0 + lg * 4 + r];
            thrv1[r] = thr[tok0 + 16 + lg * 4 + r];
        }
    }

    int vn = l15;
#pragma unroll 2
    for (int nt = 0; nt < N_EMBED / 16; ++nt) {
        const size_t boff = ((size_t)(nt * 16 + l15)) * EMB + 8 * lg;
        const short8 bh = *(const short8*)(whi + boff);
        const short8 bl = *(const short8*)(wlo + boff);
        const float cv = wwn[nt * 16 + l15];
        f32x4 c0 = {cv, cv, cv, cv};
        f32x4 c1 = {cv, cv, cv, cv};
        c0 = __builtin_amdgcn_mfma_f32_16x16x32_bf16(a0l, bh, c0, 0, 0, 0);
        c0 = __builtin_amdgcn_mfma_f32_16x16x32_bf16(a0h, bl, c0, 0, 0, 0);
        c0 = __builtin_amdgcn_mfma_f32_16x16x32_bf16(a0h, bh, c0, 0, 0, 0);
        c1 = __builtin_amdgcn_mfma_f32_16x16x32_bf16(a1l, bh, c1, 0, 0, 0);
        c1 = __builtin_amdgcn_mfma_f32_16x16x32_bf16(a1h, bl, c1, 0, 0, 0);
        c1 = __builtin_amdgcn_mfma_f32_16x16x32_bf16(a1h, bh, c1, 0, 0, 0);

        if (MODE == 0) {
#pragma unroll
            for (int r = 0; r < 4; ++r) {
                bool g0 = c0[r] > best0[r];            // strict >: first index on ties
                best0[r] = g0 ? c0[r] : best0[r];
                bid0[r]  = g0 ? vn : bid0[r];
                bool g1 = c1[r] > best1[r];
                best1[r] = g1 ? c1[r] : best1[r];
                bid1[r]  = g1 ? vn : bid1[r];
            }
        } else {
            float k0[4], k1[4];
#pragma unroll
            for (int r = 0; r < 4; ++r) { k0[r] = -2.f * c0[r]; k1[r] = -2.f * c1[r]; }
            bool f = (k0[0] <= thrv0[0]) | (k0[1] <= thrv0[1]) | (k0[2] <= thrv0[2]) |
                     (k0[3] <= thrv0[3]) | (k1[0] <= thrv1[0]) | (k1[1] <= thrv1[1]) |
                     (k1[2] <= thrv1[2]) | (k1[3] <= thrv1[3]);
            if (f) {
#pragma unroll
                for (int r = 0; r < 4; ++r) {
                    if (k0[r] <= thrv0[r]) {
                        unsigned slot = atomicAdd(ccnt, 1u);
                        if (slot < CAND_CAP)
                            cand[slot] = (((unsigned long long)(unsigned)(tok0 + lg*4 + r)) << 32) | (unsigned)vn;
                    }
                    if (k1[r] <= thrv1[r]) {
                        unsigned slot = atomicAdd(ccnt, 1u);
                        if (slot < CAND_CAP)
                            cand[slot] = (((unsigned long long)(unsigned)(tok0 + 16 + lg*4 + r)) << 32) | (unsigned)vn;
                    }
                }
            }
        }
        vn += 16;
    }

    if (MODE == 0) {
        // butterfly within each 16-lane group (offs 1..8 stay in-group)
#pragma unroll
        for (int r = 0; r < 4; ++r) {
            float b = best0[r]; int bi = bid0[r];
#pragma unroll
            for (int off = 1; off < 16; off <<= 1) {
                float ob = __shfl_xor(b, off, 64);
                int   oi = __shfl_xor(bi, off, 64);
                bool c = (ob > b) || (ob == b && oi < bi);
                b = c ? ob : b; bi = c ? oi : bi;
            }
            if (l15 == 0) packed[tok0 + lg * 4 + r] = packkey(-2.f * b, bi);

            float b1 = best1[r]; int bi1 = bid1[r];
#pragma unroll
            for (int off = 1; off < 16; off <<= 1) {
                float ob = __shfl_xor(b1, off, 64);
                int   oi = __shfl_xor(bi1, off, 64);
                bool c = (ob > b1) || (ob == b1 && oi < bi1);
                b1 = c ? ob : b1; bi1 = c ? oi : bi1;
            }
            if (l15 == 0) packed[tok0 + 16 + lg * 4 + r] = packkey(-2.f * b1, bi1);
        }
    }
}

// ============ K_exact: exact key of pass-1 candidate -> thr + packed init ============
__global__ void k_exact(const float* __restrict__ z, const float* __restrict__ weight,
                        const float* __restrict__ wwn,
                        unsigned long long* __restrict__ packed, float* __restrict__ thr) {
    int t = blockIdx.x * blockDim.x + threadIdx.x;
    int idx = (int)(packed[t] & 0xFFFFFFFFull);
    float zr[EMB];
    load_zn_row(z, t, zr);
    float key = exact_key(zr, weight + (size_t)idx * EMB, -2.f * wwn[idx]);
    thr[t] = key + EPSK;
    packed[t] = packkey(key, idx);
}

// ============ K_resolve: exact-eval flagged candidates, atomicMin ============
__global__ void k_resolve(const float* __restrict__ z, const float* __restrict__ weight,
                          const float* __restrict__ wwn,
                          const unsigned* __restrict__ ccnt,
                          const unsigned long long* __restrict__ cand,
                          unsigned long long* __restrict__ packed) {
    unsigned i = blockIdx.x * blockDim.x + threadIdx.x;
    unsigned n = *ccnt;
    if (n > CAND_CAP) n = CAND_CAP;
    if (i >= n) return;
    unsigned long long e = cand[i];
    int tok = (int)(e >> 32);
    int row = (int)(e & 0xFFFFFFFFull);
    float zr[EMB];
    load_zn_row(z, tok, zr);
    float key = exact_key(zr, weight + (size_t)row * EMB, -2.f * wwn[row]);
    atomicMin(packed + tok, packkey(key, row));
}

// ============ K_token: outputs + scatters + loss ============
__global__ void k_token(const float* __restrict__ z, const float* __restrict__ weight,
                        const unsigned long long* __restrict__ packed,
                        float* __restrict__ out, float* __restrict__ bins,
                        float* __restrict__ esum, float* __restrict__ loss) {
    int t = blockIdx.x * blockDim.x + threadIdx.x;
    int idx = (int)(packed[t] & 0xFFFFFFFFull);
    float zr[EMB];
    load_zn_row(z, t, zr);
    const float4* wp = (const float4*)(weight + (size_t)idx * EMB);
    float4* oq = (float4*)(out + OUT_ZQ + (size_t)t * EMB);

    float lacc = 0.f;
#pragma unroll
    for (int i = 0; i < 8; ++i) {
        float4 wv = wp[i];
        float zx = zr[4*i+0], zy = zr[4*i+1], zz2 = zr[4*i+2], zw = zr[4*i+3];
        float4 d, o;
        d.x = wv.x - zx; d.y = wv.y - zy; d.z = wv.z - zz2; d.w = wv.w - zw;
        lacc += d.x*d.x + d.y*d.y + d.z*d.z + d.w*d.w;
        o.x = zx + d.x; o.y = zy + d.y; o.z = zz2 + d.z; o.w = zw + d.w;
        oq[i] = o;
        atomicAdd(esum + (size_t)idx * EMB + 4*i + 0, zx);
        atomicAdd(esum + (size_t)idx * EMB + 4*i + 1, zy);
        atomicAdd(esum + (size_t)idx * EMB + 4*i + 2, zz2);
        atomicAdd(esum + (size_t)idx * EMB + 4*i + 3, zw);
    }
    out[OUT_IDX + t] = (float)idx;
    atomicAdd(bins + idx, 1.0f);
#pragma unroll
    for (int off = 32; off > 0; off >>= 1) lacc += __shfl_xor(lacc, off, 64);
    if ((threadIdx.x & 63) == 0) atomicAdd(loss, lacc);
}

// ============ K_ema: EMA codebook update + finalize loss ============
__global__ void k_ema(const float* __restrict__ weight, const float* __restrict__ cs,
                      const float* __restrict__ bins, const float* __restrict__ esum,
                      const float* __restrict__ loss, float* __restrict__ out) {
    int n = blockIdx.x * blockDim.x + threadIdx.x;
    if (n == 0) out[OUT_LOSS] = loss[0] * (1.0f / (float)(N_TOKENS * EMB));
    if (n >= N_EMBED) return;

    float b = bins[n];
    out[OUT_CS + n] = cs[n] * DECAYF + b * OMDF;
    bool zero = (b == 0.0f);
    float safe = zero ? 1.0f : b;

    float w[EMB], en[EMB];
    const float* wrow = weight + (size_t)n * EMB;
    const float* erow = esum + (size_t)n * EMB;
    float nacc = 0.f;
#pragma unroll
    for (int i = 0; i < EMB; ++i) {
        w[i] = wrow[i];
        en[i] = erow[i] / safe;
        nacc += en[i] * en[i];
    }
    float nn = fmaxf(sqrtf(nacc), 1e-12f);
#pragma unroll
    for (int i = 0; i < EMB; ++i) en[i] = zero ? w[i] : (en[i] / nn);
    float acc2 = 0.f;
    float nw[EMB];
#pragma unroll
    for (int i = 0; i < EMB; ++i) {
        nw[i] = w[i] * DECAYF + en[i] * OMDF;
        acc2 += nw[i] * nw[i];
    }
    float n2 = fmaxf(sqrtf(acc2), 1e-12f);
#pragma unroll
    for (int i = 0; i < EMB; ++i) out[OUT_NW + (size_t)n * EMB + i] = nw[i] / n2;
}

// ============ launcher ============
extern "C" void kernel_launch(void* const* d_in, const int* in_sizes, int n_in,
                              void* d_out, int out_size, void* d_ws, size_t ws_size,
                              hipStream_t stream) {
    const float* z  = (const float*)d_in[0];
    const float* w  = (const float*)d_in[1];
    const float* cs = (const float*)d_in[2];
    float* out = (float*)d_out;
    float* ws  = (float*)d_ws;

    ushortT* zhi = (ushortT*)(out + OUT_ZQ);            // 2MB, overwritten by k_token
    ushortT* zlo = zhi + (size_t)N_TOKENS * EMB;        // 2MB
    ushortT* whi = (ushortT*)(ws + WS_WHI);
    ushortT* wlo = (ushortT*)(ws + WS_WLO);
    float* wwn  = ws + WS_WWN;
    float* thr  = ws + WS_THR;
    unsigned long long* packed = (unsigned long long*)(ws + WS_PACK);
    float* bins = ws + WS_BINS;
    float* esum = ws + WS_ESUM;
    float* loss = ws + WS_LOSS;
    unsigned* ccnt = (unsigned*)(ws + WS_CCNT);
    unsigned long long* cand = (unsigned long long*)(ws + WS_CAND);

    // zero bins, esum, loss, ccnt (+pad) in one contiguous memset
    hipMemsetAsync(bins, 0, (size_t)(WS_CAND - WS_BINS) * sizeof(float), stream);

    k_prep<<<N_TOKENS / 256, 256, 0, stream>>>(z, zhi, zlo);
    k_wprep<<<N_EMBED / 256, 256, 0, stream>>>(w, whi, wlo, wwn);
    k_scan<0><<<N_TOKENS / 128, 256, 0, stream>>>(zhi, zlo, whi, wlo, wwn, thr, packed, ccnt, cand);
    k_exact<<<N_TOKENS / 256, 256, 0, stream>>>(z, w, wwn, packed, thr);
    k_scan<1><<<N_TOKENS / 128, 256, 0, stream>>>(zhi, zlo, whi, wlo, wwn, thr, packed, ccnt, cand);
    k_resolve<<<CAND_CAP / 256, 256, 0, stream>>>(z, w, wwn, ccnt, cand, packed);
    k_token<<<N_TOKENS / 256, 256, 0, stream>>>(z, w, packed, out, bins, esum, loss);
    k_ema<<<N_EMBED / 256, 256, 0, stream>>>(w, cs, bins, esum, loss, out);
}